// Round 2
// baseline (271.069 us; speedup 1.0000x reference)
//
#include <hip/hip_runtime.h>
#include <hip/hip_bf16.h>
#include <stdint.h>

typedef __bf16 bf16x8 __attribute__((ext_vector_type(8)));
typedef __bf16 bf16x4 __attribute__((ext_vector_type(4)));
typedef float  f32x4  __attribute__((ext_vector_type(4)));

#define MFMA16(a, b, c) __builtin_amdgcn_mfma_f32_16x16x32_bf16(a, b, c, 0, 0, 0)

#if __has_builtin(__builtin_amdgcn_exp2f)
#define EXP2(x) __builtin_amdgcn_exp2f(x)
#else
#define EXP2(x) exp2f(x)
#endif

// async 16B global->LDS (dest = wave-uniform base + lane*16)
__device__ __forceinline__ void ld16(void* lds, const void* g) {
    __builtin_amdgcn_global_load_lds(
        (const __attribute__((address_space(1))) void*)(uintptr_t)g,
        (__attribute__((address_space(3))) void*)(uint32_t)(uintptr_t)lds,
        16, 0, 0);
}

// ---------------- f32 -> bf16 convert (x) -------------------------------------
__global__ __launch_bounds__(256) void convert_bf16(const float* __restrict__ src,
                                                    __bf16* __restrict__ dst) {
    int i = (blockIdx.x * 256 + threadIdx.x) * 4;
    float4 v = *(const float4*)(src + i);
    dst[i]     = (__bf16)v.x;
    dst[i + 1] = (__bf16)v.y;
    dst[i + 2] = (__bf16)v.z;
    dst[i + 3] = (__bf16)v.w;
}

// ---------------- weight transpose + cast: Wt[n][k] = (bf16)W[k][n] -----------
__global__ __launch_bounds__(1024) void transpose_w(const float* __restrict__ W0,
                                                    const float* __restrict__ W1,
                                                    const float* __restrict__ W2,
                                                    const float* __restrict__ W3,
                                                    __bf16* __restrict__ dst) {
    __shared__ __bf16 t[32][33];
    const int z = blockIdx.z;
    const float* W = (z == 0) ? W0 : (z == 1) ? W1 : (z == 2) ? W2 : W3;
    __bf16* D = dst + (size_t)z * 1048576;
    const int tx = threadIdx.x, ty = threadIdx.y;
    t[ty][tx] = (__bf16)W[(size_t)(blockIdx.y * 32 + ty) * 1024 + blockIdx.x * 32 + tx];
    __syncthreads();
    D[(size_t)(blockIdx.x * 32 + ty) * 1024 + blockIdx.y * 32 + tx] = t[tx][ty];
}

// ---------------- shared GEMM mainloop: C[128x128] += A[128xK] * BT[128xK]^T ----
__device__ __forceinline__ void gemm_mainloop(const __bf16* __restrict__ A,
                                              const __bf16* __restrict__ BT,
                                              int K, __bf16* As, __bf16* Bs,
                                              f32x4 acc[4][4]) {
    const int tid  = threadIdx.x;
    const int lane = tid & 63;
    const int wid  = tid >> 6;
    const int quad = lane >> 4;
    const int l16  = lane & 15;
    const int wm   = wid >> 1;
    const int wn   = wid & 1;

    const int srow = wid * 16 + (lane >> 2);
    const int scol = (lane & 3) * 8;
    const int sdst = wid * 512 + lane * 8;

    for (int k0 = 0; k0 < K; k0 += 32) {
        ld16(As + sdst,        A  + (size_t)srow        * K + k0 + scol);
        ld16(As + 2048 + sdst, A  + (size_t)(srow + 64) * K + k0 + scol);
        ld16(Bs + sdst,        BT + (size_t)srow        * K + k0 + scol);
        ld16(Bs + 2048 + sdst, BT + (size_t)(srow + 64) * K + k0 + scol);
        __syncthreads();
        bf16x8 af[4], bf[4];
#pragma unroll
        for (int mt = 0; mt < 4; mt++)
            af[mt] = *(const bf16x8*)(As + (wm * 64 + mt * 16 + l16) * 32 + quad * 8);
#pragma unroll
        for (int nt = 0; nt < 4; nt++)
            bf[nt] = *(const bf16x8*)(Bs + (wn * 64 + nt * 16 + l16) * 32 + quad * 8);
#pragma unroll
        for (int mt = 0; mt < 4; mt++)
#pragma unroll
            for (int nt = 0; nt < 4; nt++)
                acc[mt][nt] = MFMA16(af[mt], bf[nt], acc[mt][nt]);
        __syncthreads();
    }
}

// ---------------- QKV projection: X @ W{q,k,v} + b ------------------------------
// z=0 -> Q [B,H,T,HD] PRE-SCALED by (1/8)*log2(e), z=1 -> K, z=2 -> V^T [B,H,HD,T]
__global__ __launch_bounds__(256) void qkv_gemm(const __bf16* __restrict__ X,
                                                const __bf16* __restrict__ WTb,
                                                const float* __restrict__ b0,
                                                const float* __restrict__ b1,
                                                const float* __restrict__ b2,
                                                __bf16* __restrict__ qk,
                                                __bf16* __restrict__ vt) {
    __shared__ __attribute__((aligned(16))) __bf16 As[4096];
    __shared__ __attribute__((aligned(16))) __bf16 Bs[4096];
    const int z = blockIdx.z;
    const __bf16* BT   = WTb + (size_t)z * 1048576;
    const float* bias  = (z == 0) ? b0 : (z == 1) ? b1 : b2;
    const int m0 = blockIdx.y * 128, n0 = blockIdx.x * 128;
    f32x4 acc[4][4];
    const f32x4 zz = {0.f, 0.f, 0.f, 0.f};
#pragma unroll
    for (int i = 0; i < 4; i++)
#pragma unroll
        for (int j = 0; j < 4; j++) acc[i][j] = zz;
    gemm_mainloop(X + (size_t)m0 * 1024, BT + (size_t)n0 * 1024, 1024, As, Bs, acc);

    const int lane = threadIdx.x & 63, wid = threadIdx.x >> 6;
    const int quad = lane >> 4, l16 = lane & 15, wm = wid >> 1, wn = wid & 1;
    if (z == 2) {
        // V^T epilogue: vt[((b*16+h)*64+hd)*2048 + t], 4 consecutive t packed
#pragma unroll
        for (int nt = 0; nt < 4; nt++) {
            int col = n0 + wn * 64 + nt * 16 + l16;
            float bv = bias[col];
            int h = col >> 6, hd = col & 63;
#pragma unroll
            for (int mt = 0; mt < 4; mt++) {
                int m = m0 + wm * 64 + mt * 16 + quad * 4;
                int b = m >> 11, tt = m & 2047;
                bf16x4 pk;
                pk.x = (__bf16)(acc[mt][nt].x + bv);
                pk.y = (__bf16)(acc[mt][nt].y + bv);
                pk.z = (__bf16)(acc[mt][nt].z + bv);
                pk.w = (__bf16)(acc[mt][nt].w + bv);
                *(bf16x4*)(vt + ((size_t)((b * 16 + h) * 64 + hd)) * 2048 + tt) = pk;
            }
        }
    } else {
        // softmax scale (1/sqrt(64))*log2(e) folded into Q here (z==0)
        const float sq = (z == 0) ? 0.18033688011112042f : 1.0f;
        __bf16* dst = qk + (size_t)z * 4194304;
#pragma unroll
        for (int nt = 0; nt < 4; nt++) {
            int col = n0 + wn * 64 + nt * 16 + l16;
            float bv = bias[col];
            int h = col >> 6, hd = col & 63;
#pragma unroll
            for (int mt = 0; mt < 4; mt++) {
#pragma unroll
                for (int r4 = 0; r4 < 4; r4++) {
                    int m = m0 + wm * 64 + mt * 16 + quad * 4 + r4;
                    int b = m >> 11, tt = m & 2047;
                    float v = (acc[mt][nt][r4] + bv) * sq;
                    dst[((size_t)((b * 16 + h) * 2048 + tt)) * 64 + hd] = (__bf16)v;
                }
            }
        }
    }
}

// ---------------- output projection: Y @ Wp + bp -> out [B,T,C] f32 ------------
__global__ __launch_bounds__(256) void proj_gemm(const __bf16* __restrict__ Yw,
                                                 const __bf16* __restrict__ WT,
                                                 const float* __restrict__ bias,
                                                 float* __restrict__ out) {
    __shared__ __attribute__((aligned(16))) __bf16 As[4096];
    __shared__ __attribute__((aligned(16))) __bf16 Bs[4096];
    const int m0 = blockIdx.y * 128, n0 = blockIdx.x * 128;
    f32x4 acc[4][4];
    const f32x4 zz = {0.f, 0.f, 0.f, 0.f};
#pragma unroll
    for (int i = 0; i < 4; i++)
#pragma unroll
        for (int j = 0; j < 4; j++) acc[i][j] = zz;
    gemm_mainloop(Yw + (size_t)m0 * 1024, WT + (size_t)n0 * 1024, 1024, As, Bs, acc);

    const int lane = threadIdx.x & 63, wid = threadIdx.x >> 6;
    const int quad = lane >> 4, l16 = lane & 15, wm = wid >> 1, wn = wid & 1;
#pragma unroll
    for (int nt = 0; nt < 4; nt++) {
        int col = n0 + wn * 64 + nt * 16 + l16;
        float bv = bias[col];
#pragma unroll
        for (int mt = 0; mt < 4; mt++) {
#pragma unroll
            for (int r4 = 0; r4 < 4; r4++) {
                int m = m0 + wm * 64 + mt * 16 + quad * 4 + r4;
                out[(size_t)m * 1024 + col] = acc[mt][nt][r4] + bv;
            }
        }
    }
}

// ---------------- flash attention v6 -------------------------------------------
// v5 post-mortem: XCD remap cut FETCH 19->12 MB but time only -5% -> kernel is
// LATENCY x OCCUPANCY bound, not BW bound (Little's law: ~8 waves/CU x 256 B
// in flight = ~2 KB/CU -> ~10 B/cy vs L2's 56 B/cy capability).
// v6: raise residency 2 -> 4 blocks/CU.
//   (a) S^T phase restructured into two key-halves of 4 mt-tiles so only
//       accs[4][2] (32 VGPR) is live at once instead of accs[8][2] (64).
//       FP summation order unchanged (half0 mt0-3, half1 mt0-3 == mt0-7).
//   (b) __launch_bounds__(256, 4): cap 128 VGPR/wave -> 16 waves/CU.
//       LDS 4 x 35840 B = 143 KB <= 160 KB. Grid 1024 = exactly 4/CU, no tail.
// Everything else (XCD remap, pairing, no-max softmax, merge) unchanged.
__global__ __launch_bounds__(256, 4) void attn_kernel(const __bf16* __restrict__ Qg,
                                                      const __bf16* __restrict__ Kg,
                                                      const __bf16* __restrict__ Vtg,
                                                      __bf16* __restrict__ Y) {
    // Ps: per-wave P staging (32x136 bf16, 8704 B each). In the merge phase
    // wave w's slice is reused (exact alias) as its f32 partial Om[32*68].
    __shared__ __attribute__((aligned(16))) __bf16 Ps[4][32 * 136];
    __shared__ __attribute__((aligned(16))) float  Lw[4][32];   // per-wave l
    __shared__ __attribute__((aligned(16))) float  Linv[32];    // 1/l merged

    const int tid  = threadIdx.x;
    const int lane = tid & 63;
    const int wid  = tid >> 6;
    const int quad = lane >> 4;
    const int l16  = lane & 15;
    const int p    = blockIdx.x;
    const int xcd  = p & 7;    // round-robin dispatch: block -> XCD = blockIdx % 8
    const int j    = p >> 3;   // 0..127 within this XCD's block group
    const f32x4 zz = {0.f, 0.f, 0.f, 0.f};

#pragma unroll 1
    for (int itm = 0; itm < 2; itm++) {
        // local item id within XCD group: pair {j, 255-j} -> bx, 63-bx (balanced)
        const int l   = itm ? (255 - j) : j;
        const int bx  = l >> 2;
        const int bh  = (xcd << 2) + (l & 3);   // 4 heads per XCD -> L2-resident K/V
        const int q0  = bx * 32;
        const int ktlast = bx >> 2;
        const size_t hbase = (size_t)bh * (2048 * 64);

        // Q fragments (B-layout, pre-scaled) for the item's 32 q rows
        bf16x8 qf[2][2];
#pragma unroll
        for (int nt = 0; nt < 2; nt++)
#pragma unroll
            for (int kk = 0; kk < 2; kk++)
                qf[nt][kk] = *(const bf16x8*)(Qg + hbase +
                                              (size_t)(q0 + nt * 16 + l16) * 64 +
                                              kk * 32 + quad * 8);

        f32x4 acc_o[2][4];
#pragma unroll
        for (int i = 0; i < 2; i++)
#pragma unroll
            for (int jj = 0; jj < 4; jj++) acc_o[i][jj] = zz;
        float l_s[2] = {0.f, 0.f};

        for (int kt = wid; kt <= ktlast; kt += 4) {
            const int key0 = kt << 7;
            float s_s[2] = {0.f, 0.f};

            // ---- S^T = K * Q^T in two key-halves of 64 (32 VGPR acc live) ----
#pragma unroll
            for (int half = 0; half < 2; half++) {
                const int koff = key0 + half * 64;
                f32x4 accs[4][2];
#pragma unroll
                for (int mt = 0; mt < 4; mt++) { accs[mt][0] = zz; accs[mt][1] = zz; }
#pragma unroll
                for (int kk = 0; kk < 2; kk++) {
#pragma unroll
                    for (int mt = 0; mt < 4; mt++) {
                        bf16x8 kf = *(const bf16x8*)(Kg + hbase +
                                                     (size_t)(koff + mt * 16 + l16) * 64 +
                                                     kk * 32 + quad * 8);
                        accs[mt][0] = MFMA16(kf, qf[0][kk], accs[mt][0]);
                        accs[mt][1] = MFMA16(kf, qf[1][kk], accs[mt][1]);
                    }
                }

                // causal mask (diag tile only; scale already folded into Q)
                if (kt == ktlast) {
#pragma unroll
                    for (int mt = 0; mt < 4; mt++)
#pragma unroll
                        for (int nt = 0; nt < 2; nt++) {
                            int q_g = q0 + nt * 16 + l16;
#pragma unroll
                            for (int r4 = 0; r4 < 4; r4++) {
                                int key_g = koff + mt * 16 + quad * 4 + r4;
                                if (key_g > q_g) accs[mt][nt][r4] = -1e30f;
                            }
                        }
                }

                // P = exp2(S^T), no max subtraction; b64 stores to P[q][key]
#pragma unroll
                for (int mt = 0; mt < 4; mt++)
#pragma unroll
                    for (int nt = 0; nt < 2; nt++) {
                        f32x4 pv;
                        pv.x = EXP2(accs[mt][nt].x);
                        pv.y = EXP2(accs[mt][nt].y);
                        pv.z = EXP2(accs[mt][nt].z);
                        pv.w = EXP2(accs[mt][nt].w);
                        s_s[nt] += (pv.x + pv.y) + (pv.z + pv.w);
                        bf16x4 pk;
                        pk.x = (__bf16)pv.x; pk.y = (__bf16)pv.y;
                        pk.z = (__bf16)pv.z; pk.w = (__bf16)pv.w;
                        *(bf16x4*)(&Ps[wid][(nt * 16 + l16) * 136 +
                                            half * 64 + mt * 16 + quad * 4]) = pk;
                    }
            }

#pragma unroll
            for (int nt = 0; nt < 2; nt++) {
                float t = s_s[nt];
                t += __shfl_xor(t, 16);
                t += __shfl_xor(t, 32);
                l_s[nt] += t;
            }

            // ---- O += P * V (A=P from own-wave LDS b128, B=V^T direct global) ----
#pragma unroll
            for (int kk = 0; kk < 4; kk++) {
                bf16x8 pf[2], vf[4];
#pragma unroll
                for (int mtP = 0; mtP < 2; mtP++)
                    pf[mtP] = *(const bf16x8*)(&Ps[wid][(mtP * 16 + l16) * 136 +
                                                        kk * 32 + quad * 8]);
#pragma unroll
                for (int nv = 0; nv < 4; nv++)
                    vf[nv] = *(const bf16x8*)(Vtg + hbase +
                                              (size_t)(nv * 16 + l16) * 2048 +
                                              key0 + kk * 32 + quad * 8);
#pragma unroll
                for (int mtP = 0; mtP < 2; mtP++)
#pragma unroll
                    for (int nv = 0; nv < 4; nv++)
                        acc_o[mtP][nv] = MFMA16(pf[mtP], vf[nv], acc_o[mtP][nv]);
            }
        }

        // ================= merge of 4 key-split partials (sum only) =============
        if (quad == 0) { Lw[wid][l16] = l_s[0]; Lw[wid][16 + l16] = l_s[1]; }
        __syncthreads();
        if (wid == 0 && quad == 0) {
#pragma unroll
            for (int nt = 0; nt < 2; nt++) {
                int qq = nt * 16 + l16;
                Linv[qq] = 1.0f / (Lw[0][qq] + Lw[1][qq] + Lw[2][qq] + Lw[3][qq]);
            }
        }
        // own-wave slice of Ps reused as f32 partial: Om[32 rows][68 stride]
        float* Om = (float*)&Ps[0][0];
#pragma unroll
        for (int mtP = 0; mtP < 2; mtP++)
#pragma unroll
            for (int nv = 0; nv < 4; nv++)
#pragma unroll
                for (int r4 = 0; r4 < 4; r4++)
                    Om[wid * 2176 + (mtP * 16 + quad * 4 + r4) * 68 + nv * 16 + l16] =
                        acc_o[mtP][nv][r4];
        __syncthreads();

        // sum 4 partials, scale by 1/l, write Y (16B coalesced)
        {
            const int q  = tid >> 3;          // 0..31
            const int c0 = (tid & 7) * 8;     // 0..56
            f32x4 s0 = zz, s1 = zz;
#pragma unroll
            for (int w = 0; w < 4; w++) {
                s0 += *(const f32x4*)(&Om[w * 2176 + q * 68 + c0]);
                s1 += *(const f32x4*)(&Om[w * 2176 + q * 68 + c0 + 4]);
            }
            float li = Linv[q];
            bf16x8 o;
            o[0] = (__bf16)(s0.x * li); o[1] = (__bf16)(s0.y * li);
            o[2] = (__bf16)(s0.z * li); o[3] = (__bf16)(s0.w * li);
            o[4] = (__bf16)(s1.x * li); o[5] = (__bf16)(s1.y * li);
            o[6] = (__bf16)(s1.z * li); o[7] = (__bf16)(s1.w * li);
            const int b = bh >> 4, h = bh & 15;
            *(bf16x8*)(Y + ((size_t)(b * 2048 + q0 + q)) * 1024 + h * 64 + c0) = o;
        }
        __syncthreads();   // protect Ps/Lw reuse by the next item
    }
}

// ws layout (bf16 elems), 40 MB total:
// [0,4Mi)     x as bf16 (dead after qkv) -> reused as Y [B,T,C]
// [4Mi,8Mi)   W^T x4 (Wq,Wk,Wv,Wp)
// [8Mi,12Mi)  Q [B,H,T,HD] (pre-scaled)
// [12Mi,16Mi) K [B,H,T,HD]
// [16Mi,20Mi) V^T [B,H,HD,T]  (written directly by qkv_gemm z=2)
#define XB_OFF  0
#define WT_OFF  4194304
#define Q_OFF   8388608
#define K_OFF   12582912
#define VT_OFF  16777216
#define Y_OFF   0

extern "C" void kernel_launch(void* const* d_in, const int* in_sizes, int n_in,
                              void* d_out, int out_size, void* d_ws, size_t ws_size,
                              hipStream_t stream) {
    const float* x  = (const float*)d_in[0];
    const float* Wq = (const float*)d_in[1];
    const float* bq = (const float*)d_in[2];
    const float* Wk = (const float*)d_in[3];
    const float* bk = (const float*)d_in[4];
    const float* Wv = (const float*)d_in[5];
    const float* bv = (const float*)d_in[6];
    const float* Wp = (const float*)d_in[7];
    const float* bp = (const float*)d_in[8];
    __bf16* ws  = (__bf16*)d_ws;
    float*  out = (float*)d_out;
    if (ws_size < (size_t)41943040) return;  // need 40 MB scratch

    convert_bf16<<<4096, 256, 0, stream>>>(x, ws + XB_OFF);
    transpose_w<<<dim3(32, 32, 4), dim3(32, 32), 0, stream>>>(Wq, Wk, Wv, Wp, ws + WT_OFF);
    qkv_gemm<<<dim3(8, 32, 3), 256, 0, stream>>>(ws + XB_OFF, ws + WT_OFF, bq, bk, bv,
                                                 ws + Q_OFF, ws + VT_OFF);
    attn_kernel<<<dim3(1024), 256, 0, stream>>>(ws + Q_OFF, ws + K_OFF, ws + VT_OFF,
                                                ws + Y_OFF);
    proj_gemm<<<dim3(8, 32), 256, 0, stream>>>(ws + Y_OFF, ws + WT_OFF + 3 * 1048576, bp, out);
}

// Round 3
// 209.089 us; speedup vs baseline: 1.2964x; 1.2964x over previous
//
#include <hip/hip_runtime.h>
#include <hip/hip_bf16.h>
#include <stdint.h>

typedef __bf16 bf16x8 __attribute__((ext_vector_type(8)));
typedef __bf16 bf16x4 __attribute__((ext_vector_type(4)));
typedef float  f32x4  __attribute__((ext_vector_type(4)));

#define MFMA16(a, b, c) __builtin_amdgcn_mfma_f32_16x16x32_bf16(a, b, c, 0, 0, 0)

#if __has_builtin(__builtin_amdgcn_exp2f)
#define EXP2(x) __builtin_amdgcn_exp2f(x)
#else
#define EXP2(x) exp2f(x)
#endif

// async 16B global->LDS (dest = wave-uniform base + lane*16)
__device__ __forceinline__ void ld16(void* lds, const void* g) {
    __builtin_amdgcn_global_load_lds(
        (const __attribute__((address_space(1))) void*)(uintptr_t)g,
        (__attribute__((address_space(3))) void*)(uint32_t)(uintptr_t)lds,
        16, 0, 0);
}

// ---------------- f32 -> bf16 convert (x) -------------------------------------
__global__ __launch_bounds__(256) void convert_bf16(const float* __restrict__ src,
                                                    __bf16* __restrict__ dst) {
    int i = (blockIdx.x * 256 + threadIdx.x) * 4;
    float4 v = *(const float4*)(src + i);
    dst[i]     = (__bf16)v.x;
    dst[i + 1] = (__bf16)v.y;
    dst[i + 2] = (__bf16)v.z;
    dst[i + 3] = (__bf16)v.w;
}

// ---------------- weight transpose + cast: Wt[n][k] = (bf16)W[k][n] -----------
__global__ __launch_bounds__(1024) void transpose_w(const float* __restrict__ W0,
                                                    const float* __restrict__ W1,
                                                    const float* __restrict__ W2,
                                                    const float* __restrict__ W3,
                                                    __bf16* __restrict__ dst) {
    __shared__ __bf16 t[32][33];
    const int z = blockIdx.z;
    const float* W = (z == 0) ? W0 : (z == 1) ? W1 : (z == 2) ? W2 : W3;
    __bf16* D = dst + (size_t)z * 1048576;
    const int tx = threadIdx.x, ty = threadIdx.y;
    t[ty][tx] = (__bf16)W[(size_t)(blockIdx.y * 32 + ty) * 1024 + blockIdx.x * 32 + tx];
    __syncthreads();
    D[(size_t)(blockIdx.x * 32 + ty) * 1024 + blockIdx.y * 32 + tx] = t[tx][ty];
}

// ---------------- shared GEMM mainloop: C[128x128] += A[128xK] * BT[128xK]^T ----
__device__ __forceinline__ void gemm_mainloop(const __bf16* __restrict__ A,
                                              const __bf16* __restrict__ BT,
                                              int K, __bf16* As, __bf16* Bs,
                                              f32x4 acc[4][4]) {
    const int tid  = threadIdx.x;
    const int lane = tid & 63;
    const int wid  = tid >> 6;
    const int quad = lane >> 4;
    const int l16  = lane & 15;
    const int wm   = wid >> 1;
    const int wn   = wid & 1;

    const int srow = wid * 16 + (lane >> 2);
    const int scol = (lane & 3) * 8;
    const int sdst = wid * 512 + lane * 8;

    for (int k0 = 0; k0 < K; k0 += 32) {
        ld16(As + sdst,        A  + (size_t)srow        * K + k0 + scol);
        ld16(As + 2048 + sdst, A  + (size_t)(srow + 64) * K + k0 + scol);
        ld16(Bs + sdst,        BT + (size_t)srow        * K + k0 + scol);
        ld16(Bs + 2048 + sdst, BT + (size_t)(srow + 64) * K + k0 + scol);
        __syncthreads();
        bf16x8 af[4], bf[4];
#pragma unroll
        for (int mt = 0; mt < 4; mt++)
            af[mt] = *(const bf16x8*)(As + (wm * 64 + mt * 16 + l16) * 32 + quad * 8);
#pragma unroll
        for (int nt = 0; nt < 4; nt++)
            bf[nt] = *(const bf16x8*)(Bs + (wn * 64 + nt * 16 + l16) * 32 + quad * 8);
#pragma unroll
        for (int mt = 0; mt < 4; mt++)
#pragma unroll
            for (int nt = 0; nt < 4; nt++)
                acc[mt][nt] = MFMA16(af[mt], bf[nt], acc[mt][nt]);
        __syncthreads();
    }
}

// ---------------- QKV projection: X @ W{q,k,v} + b ------------------------------
// z=0 -> Q [B,H,T,HD] PRE-SCALED by (1/8)*log2(e), z=1 -> K, z=2 -> V^T [B,H,HD,T]
__global__ __launch_bounds__(256) void qkv_gemm(const __bf16* __restrict__ X,
                                                const __bf16* __restrict__ WTb,
                                                const float* __restrict__ b0,
                                                const float* __restrict__ b1,
                                                const float* __restrict__ b2,
                                                __bf16* __restrict__ qk,
                                                __bf16* __restrict__ vt) {
    __shared__ __attribute__((aligned(16))) __bf16 As[4096];
    __shared__ __attribute__((aligned(16))) __bf16 Bs[4096];
    const int z = blockIdx.z;
    const __bf16* BT   = WTb + (size_t)z * 1048576;
    const float* bias  = (z == 0) ? b0 : (z == 1) ? b1 : b2;
    const int m0 = blockIdx.y * 128, n0 = blockIdx.x * 128;
    f32x4 acc[4][4];
    const f32x4 zz = {0.f, 0.f, 0.f, 0.f};
#pragma unroll
    for (int i = 0; i < 4; i++)
#pragma unroll
        for (int j = 0; j < 4; j++) acc[i][j] = zz;
    gemm_mainloop(X + (size_t)m0 * 1024, BT + (size_t)n0 * 1024, 1024, As, Bs, acc);

    const int lane = threadIdx.x & 63, wid = threadIdx.x >> 6;
    const int quad = lane >> 4, l16 = lane & 15, wm = wid >> 1, wn = wid & 1;
    if (z == 2) {
        // V^T epilogue: vt[((b*16+h)*64+hd)*2048 + t], 4 consecutive t packed
#pragma unroll
        for (int nt = 0; nt < 4; nt++) {
            int col = n0 + wn * 64 + nt * 16 + l16;
            float bv = bias[col];
            int h = col >> 6, hd = col & 63;
#pragma unroll
            for (int mt = 0; mt < 4; mt++) {
                int m = m0 + wm * 64 + mt * 16 + quad * 4;
                int b = m >> 11, tt = m & 2047;
                bf16x4 pk;
                pk.x = (__bf16)(acc[mt][nt].x + bv);
                pk.y = (__bf16)(acc[mt][nt].y + bv);
                pk.z = (__bf16)(acc[mt][nt].z + bv);
                pk.w = (__bf16)(acc[mt][nt].w + bv);
                *(bf16x4*)(vt + ((size_t)((b * 16 + h) * 64 + hd)) * 2048 + tt) = pk;
            }
        }
    } else {
        // softmax scale (1/sqrt(64))*log2(e) folded into Q here (z==0)
        const float sq = (z == 0) ? 0.18033688011112042f : 1.0f;
        __bf16* dst = qk + (size_t)z * 4194304;
#pragma unroll
        for (int nt = 0; nt < 4; nt++) {
            int col = n0 + wn * 64 + nt * 16 + l16;
            float bv = bias[col];
            int h = col >> 6, hd = col & 63;
#pragma unroll
            for (int mt = 0; mt < 4; mt++) {
#pragma unroll
                for (int r4 = 0; r4 < 4; r4++) {
                    int m = m0 + wm * 64 + mt * 16 + quad * 4 + r4;
                    int b = m >> 11, tt = m & 2047;
                    float v = (acc[mt][nt][r4] + bv) * sq;
                    dst[((size_t)((b * 16 + h) * 2048 + tt)) * 64 + hd] = (__bf16)v;
                }
            }
        }
    }
}

// ---------------- output projection: Y @ Wp + bp -> out [B,T,C] f32 ------------
__global__ __launch_bounds__(256) void proj_gemm(const __bf16* __restrict__ Yw,
                                                 const __bf16* __restrict__ WT,
                                                 const float* __restrict__ bias,
                                                 float* __restrict__ out) {
    __shared__ __attribute__((aligned(16))) __bf16 As[4096];
    __shared__ __attribute__((aligned(16))) __bf16 Bs[4096];
    const int m0 = blockIdx.y * 128, n0 = blockIdx.x * 128;
    f32x4 acc[4][4];
    const f32x4 zz = {0.f, 0.f, 0.f, 0.f};
#pragma unroll
    for (int i = 0; i < 4; i++)
#pragma unroll
        for (int j = 0; j < 4; j++) acc[i][j] = zz;
    gemm_mainloop(Yw + (size_t)m0 * 1024, WT + (size_t)n0 * 1024, 1024, As, Bs, acc);

    const int lane = threadIdx.x & 63, wid = threadIdx.x >> 6;
    const int quad = lane >> 4, l16 = lane & 15, wm = wid >> 1, wn = wid & 1;
#pragma unroll
    for (int nt = 0; nt < 4; nt++) {
        int col = n0 + wn * 64 + nt * 16 + l16;
        float bv = bias[col];
#pragma unroll
        for (int mt = 0; mt < 4; mt++) {
#pragma unroll
            for (int r4 = 0; r4 < 4; r4++) {
                int m = m0 + wm * 64 + mt * 16 + quad * 4 + r4;
                out[(size_t)m * 1024 + col] = acc[mt][nt][r4] + bv;
            }
        }
    }
}

// ---------------- flash attention v7: q-split waves + LDS-shared K/V ------------
// v5/v6 post-mortem: v5 moved 557 MB of wave-private K/V traffic at 7.4 TB/s
// aggregate (L1<-L2) = the binding constraint (XCD remap -5%, occupancy cap ->
// spills). v7 cuts the traffic 4x: the 4 waves q-SPLIT a 128-q item (32 q rows
// each), all walking the SAME key range; K/V tiles staged once per kt step into
// double-buffered LDS via global_load_lds and shared by all waves. Key-split
// merge phase deleted (each wave owns its rows' full l and O).
//   - LDS row stride 128B/256B would be a 16-way bank conflict on ds_read_b128;
//     fixed by XOR swizzle slot^=(row&7), applied BOTH sides (rule 21): the
//     global SOURCE lane address is pre-swizzled (LDS dest of global_load_lds is
//     linear), ds_reads swizzle the slot. 8 lanes/4-bank group = conflict-free.
//   - Items paired {i, 15-i} per head: 17 kt steps/block, flat. 256 blocks =
//     1/CU. head = ((b&7)<<2)+((b>>3)&3): 4 heads per XCD -> K/V L2-resident.
//   - NO-MAX softmax unchanged (scale pre-folded into Q; masked -1e30 -> 0).
//   - launch_bounds(256,1): no VGPR cap -> no spill (v6 lesson).
__global__ __launch_bounds__(256, 1) void attn_kernel(const __bf16* __restrict__ Qg,
                                                      const __bf16* __restrict__ Kg,
                                                      const __bf16* __restrict__ Vtg,
                                                      __bf16* __restrict__ Y) {
    __shared__ __attribute__((aligned(16))) __bf16 Kb[2][128 * 64];  // [key][d] swz
    __shared__ __attribute__((aligned(16))) __bf16 Vb[2][64 * 128];  // [d][key] swz
    __shared__ __attribute__((aligned(16))) __bf16 Ps[4][32 * 136];  // per-wave P
    __shared__ __attribute__((aligned(16))) float  Lw[4][32];        // per-wave l

    const int tid  = threadIdx.x;
    const int lane = tid & 63;
    const int wid  = tid >> 6;
    const int quad = lane >> 4;
    const int l16  = lane & 15;
    const int bkid = blockIdx.x;
    const int head  = ((bkid & 7) << 2) + ((bkid >> 3) & 3);  // 4 heads per XCD
    const int ipair = bkid >> 5;                              // 0..7
    const size_t hbase = (size_t)head * (2048 * 64);
    const f32x4 zz = {0.f, 0.f, 0.f, 0.f};

    // staging per-lane constants (source pre-swizzle; LDS dest stays linear)
    const int kr  = lane >> 3;            // K row-in-chunk (= row&7)
    const int kc8 = (lane & 7) ^ kr;      // K swizzled 16B slot
    const int vr  = lane >> 4;            // V row-in-chunk
    const int vl  = lane & 15;

#pragma unroll 1
    for (int itm = 0; itm < 2; itm++) {
        const int qi  = itm ? (15 - ipair) : ipair;  // q-tile index == last key tile
        const int ktl = qi;
        const int q0  = qi << 7;
        const int q0w = q0 + wid * 32;

        // Q fragments (B-layout, pre-scaled) for this wave's 32 q rows
        bf16x8 qf[2][2];
#pragma unroll
        for (int nt = 0; nt < 2; nt++)
#pragma unroll
            for (int kk = 0; kk < 2; kk++)
                qf[nt][kk] = *(const bf16x8*)(Qg + hbase +
                                              (size_t)(q0w + nt * 16 + l16) * 64 +
                                              kk * 32 + quad * 8);

        f32x4 acc_o[2][4];
#pragma unroll
        for (int i = 0; i < 2; i++)
#pragma unroll
            for (int jj = 0; jj < 4; jj++) acc_o[i][jj] = zz;
        float l_s[2] = {0.f, 0.f};

        // ---- staging: wave wid stages K chunks 4w..4w+3 (8 rows each) and
        //      V chunks 4w..4w+3 (4 d-rows each); source addr pre-swizzled ----
        auto stage = [&](int bf, int key0) {
#pragma unroll
            for (int i = 0; i < 4; i++) {
                const int c = wid * 4 + i;
                ld16((char*)&Kb[bf][0] + c * 1024 + lane * 16,
                     Kg + hbase + (size_t)(key0 + c * 8 + kr) * 64 + kc8 * 8);
            }
#pragma unroll
            for (int i = 0; i < 4; i++) {
                const int c = wid * 4 + i;
                const int row = c * 4 + vr;
                const int vc  = vl ^ (row & 7);
                ld16((char*)&Vb[bf][0] + c * 1024 + lane * 16,
                     Vtg + hbase + (size_t)row * 2048 + key0 + vc * 8);
            }
        };

        stage(0, 0);
        __syncthreads();   // compiler drains vmcnt before barrier
        int buf = 0;

#pragma unroll 1
        for (int kt = 0; kt <= ktl; kt++) {
            if (kt < ktl) stage(buf ^ 1, (kt + 1) << 7);  // prefetch next tile

            // ---- S^T = K * Q^T from LDS K (swizzled read) ----
            f32x4 accs[8][2];
#pragma unroll
            for (int mt = 0; mt < 8; mt++) { accs[mt][0] = zz; accs[mt][1] = zz; }
#pragma unroll
            for (int kk = 0; kk < 2; kk++) {
#pragma unroll
                for (int mt = 0; mt < 8; mt++) {
                    bf16x8 kf = *(const bf16x8*)(&Kb[buf][(mt * 16 + l16) * 64 +
                                                 (((kk * 4 + quad) ^ (l16 & 7)) << 3)]);
                    accs[mt][0] = MFMA16(kf, qf[0][kk], accs[mt][0]);
                    accs[mt][1] = MFMA16(kf, qf[1][kk], accs[mt][1]);
                }
            }

            // ---- causal mask (diag tile only: item q range == tile ktl) ----
            if (kt == ktl) {
#pragma unroll
                for (int mt = 0; mt < 8; mt++)
#pragma unroll
                    for (int nt = 0; nt < 2; nt++) {
                        int q_g = wid * 32 + nt * 16 + l16;        // rel to q0
#pragma unroll
                        for (int r4 = 0; r4 < 4; r4++) {
                            int key_g = mt * 16 + quad * 4 + r4;   // rel to q0
                            if (key_g > q_g) accs[mt][nt][r4] = -1e30f;
                        }
                    }
            }

            // ---- P = exp2(S^T), no max subtraction; stores to P[q][key] ----
            float s_s[2] = {0.f, 0.f};
#pragma unroll
            for (int mt = 0; mt < 8; mt++)
#pragma unroll
                for (int nt = 0; nt < 2; nt++) {
                    f32x4 pv;
                    pv.x = EXP2(accs[mt][nt].x);
                    pv.y = EXP2(accs[mt][nt].y);
                    pv.z = EXP2(accs[mt][nt].z);
                    pv.w = EXP2(accs[mt][nt].w);
                    s_s[nt] += (pv.x + pv.y) + (pv.z + pv.w);
                    bf16x4 pk;
                    pk.x = (__bf16)pv.x; pk.y = (__bf16)pv.y;
                    pk.z = (__bf16)pv.z; pk.w = (__bf16)pv.w;
                    *(bf16x4*)(&Ps[wid][(nt * 16 + l16) * 136 + mt * 16 + quad * 4]) = pk;
                }
#pragma unroll
            for (int nt = 0; nt < 2; nt++) {
                float t = s_s[nt];
                t += __shfl_xor(t, 16);
                t += __shfl_xor(t, 32);
                l_s[nt] += t;
            }

            // ---- O += P * V (A=P own-wave LDS, B=V shared LDS swizzled) ----
#pragma unroll
            for (int kk = 0; kk < 4; kk++) {
                bf16x8 pf[2], vf[4];
#pragma unroll
                for (int mtP = 0; mtP < 2; mtP++)
                    pf[mtP] = *(const bf16x8*)(&Ps[wid][(mtP * 16 + l16) * 136 +
                                                        kk * 32 + quad * 8]);
#pragma unroll
                for (int nv = 0; nv < 4; nv++)
                    vf[nv] = *(const bf16x8*)(&Vb[buf][(nv * 16 + l16) * 128 +
                                              (((kk * 4 + quad) ^ (l16 & 7)) << 3)]);
#pragma unroll
                for (int mtP = 0; mtP < 2; mtP++)
#pragma unroll
                    for (int nv = 0; nv < 4; nv++)
                        acc_o[mtP][nv] = MFMA16(pf[mtP], vf[nv], acc_o[mtP][nv]);
            }

            __syncthreads();   // all waves done reading buf; staged buf^1 landed
            buf ^= 1;
        }

        // ================= epilogue (wave-owns-rows: no merge) ==================
        if (quad == 0) { Lw[wid][l16] = l_s[0]; Lw[wid][16 + l16] = l_s[1]; }
        // own-wave Ps slice reused as f32 O transpose buffer: [32 q][68 stride]
        float* Om = (float*)&Ps[wid][0];
#pragma unroll
        for (int mtP = 0; mtP < 2; mtP++)
#pragma unroll
            for (int nv = 0; nv < 4; nv++)
#pragma unroll
                for (int r4 = 0; r4 < 4; r4++)
                    Om[(mtP * 16 + quad * 4 + r4) * 68 + nv * 16 + l16] =
                        acc_o[mtP][nv][r4];
        __syncthreads();

        // scale by 1/l, write Y (16B coalesced): lane -> (q = lane/2, 32-d half)
        {
            const int q  = lane >> 1;
            const int d0 = (lane & 1) * 32;
            float li = 1.0f / Lw[wid][q];
            f32x4 s[8];
#pragma unroll
            for (int jj = 0; jj < 8; jj++)
                s[jj] = *(const f32x4*)(&Om[q * 68 + d0 + jj * 4]);
            bf16x8 o0, o1;
#pragma unroll
            for (int e = 0; e < 4; e++) {
                o0[e]     = (__bf16)(s[0][e] * li); o0[e + 4] = (__bf16)(s[1][e] * li);
                o1[e]     = (__bf16)(s[4][e] * li); o1[e + 4] = (__bf16)(s[5][e] * li);
            }
#pragma unroll
            for (int e = 0; e < 4; e++) {
                // s[2],s[3] -> o0 upper? no: layout is linear d: s[j] covers d0+4j
            }
            // linear pack: d = d0 + 0..15 -> o0, d0 + 16..31 -> o1
            o0[0] = (__bf16)(s[0][0] * li); o0[1] = (__bf16)(s[0][1] * li);
            o0[2] = (__bf16)(s[0][2] * li); o0[3] = (__bf16)(s[0][3] * li);
            o0[4] = (__bf16)(s[1][0] * li); o0[5] = (__bf16)(s[1][1] * li);
            o0[6] = (__bf16)(s[1][2] * li); o0[7] = (__bf16)(s[1][3] * li);
            o1[0] = (__bf16)(s[2][0] * li); o1[1] = (__bf16)(s[2][1] * li);
            o1[2] = (__bf16)(s[2][2] * li); o1[3] = (__bf16)(s[2][3] * li);
            o1[4] = (__bf16)(s[3][0] * li); o1[5] = (__bf16)(s[3][1] * li);
            o1[6] = (__bf16)(s[3][2] * li); o1[7] = (__bf16)(s[3][3] * li);
            bf16x8 o2, o3;
            o2[0] = (__bf16)(s[4][0] * li); o2[1] = (__bf16)(s[4][1] * li);
            o2[2] = (__bf16)(s[4][2] * li); o2[3] = (__bf16)(s[4][3] * li);
            o2[4] = (__bf16)(s[5][0] * li); o2[5] = (__bf16)(s[5][1] * li);
            o2[6] = (__bf16)(s[5][2] * li); o2[7] = (__bf16)(s[5][3] * li);
            o3[0] = (__bf16)(s[6][0] * li); o3[1] = (__bf16)(s[6][1] * li);
            o3[2] = (__bf16)(s[6][2] * li); o3[3] = (__bf16)(s[6][3] * li);
            o3[4] = (__bf16)(s[7][0] * li); o3[5] = (__bf16)(s[7][1] * li);
            o3[6] = (__bf16)(s[7][2] * li); o3[7] = (__bf16)(s[7][3] * li);
            const int bb = head >> 4, hh = head & 15;
            __bf16* yp = Y + ((size_t)(bb * 2048 + q0w + q)) * 1024 + hh * 64 + d0;
            *(bf16x8*)(yp)      = o0;
            *(bf16x8*)(yp + 8)  = o1;
            *(bf16x8*)(yp + 16) = o2;
            *(bf16x8*)(yp + 24) = o3;
        }
        __syncthreads();   // protect Kb/Vb/Ps reuse by the next item
    }
}

// ws layout (bf16 elems), 40 MB total:
// [0,4Mi)     x as bf16 (dead after qkv) -> reused as Y [B,T,C]
// [4Mi,8Mi)   W^T x4 (Wq,Wk,Wv,Wp)
// [8Mi,12Mi)  Q [B,H,T,HD] (pre-scaled)
// [12Mi,16Mi) K [B,H,T,HD]
// [16Mi,20Mi) V^T [B,H,HD,T]  (written directly by qkv_gemm z=2)
#define XB_OFF  0
#define WT_OFF  4194304
#define Q_OFF   8388608
#define K_OFF   12582912
#define VT_OFF  16777216
#define Y_OFF   0

extern "C" void kernel_launch(void* const* d_in, const int* in_sizes, int n_in,
                              void* d_out, int out_size, void* d_ws, size_t ws_size,
                              hipStream_t stream) {
    const float* x  = (const float*)d_in[0];
    const float* Wq = (const float*)d_in[1];
    const float* bq = (const float*)d_in[2];
    const float* Wk = (const float*)d_in[3];
    const float* bk = (const float*)d_in[4];
    const float* Wv = (const float*)d_in[5];
    const float* bv = (const float*)d_in[6];
    const float* Wp = (const float*)d_in[7];
    const float* bp = (const float*)d_in[8];
    __bf16* ws  = (__bf16*)d_ws;
    float*  out = (float*)d_out;
    if (ws_size < (size_t)41943040) return;  // need 40 MB scratch

    convert_bf16<<<4096, 256, 0, stream>>>(x, ws + XB_OFF);
    transpose_w<<<dim3(32, 32, 4), dim3(32, 32), 0, stream>>>(Wq, Wk, Wv, Wp, ws + WT_OFF);
    qkv_gemm<<<dim3(8, 32, 3), 256, 0, stream>>>(ws + XB_OFF, ws + WT_OFF, bq, bk, bv,
                                                 ws + Q_OFF, ws + VT_OFF);
    attn_kernel<<<dim3(256), 256, 0, stream>>>(ws + Q_OFF, ws + K_OFF, ws + VT_OFF,
                                               ws + Y_OFF);
    proj_gemm<<<dim3(8, 32), 256, 0, stream>>>(ws + Y_OFF, ws + WT_OFF + 3 * 1048576, bp, out);
}

// Round 4
// 188.257 us; speedup vs baseline: 1.4399x; 1.1107x over previous
//
#include <hip/hip_runtime.h>
#include <hip/hip_bf16.h>
#include <stdint.h>

typedef __bf16 bf16x8 __attribute__((ext_vector_type(8)));
typedef __bf16 bf16x4 __attribute__((ext_vector_type(4)));
typedef float  f32x4  __attribute__((ext_vector_type(4)));

#define MFMA16(a, b, c) __builtin_amdgcn_mfma_f32_16x16x32_bf16(a, b, c, 0, 0, 0)

#if __has_builtin(__builtin_amdgcn_exp2f)
#define EXP2(x) __builtin_amdgcn_exp2f(x)
#else
#define EXP2(x) exp2f(x)
#endif

// async 16B global->LDS (dest = wave-uniform base + lane*16)
__device__ __forceinline__ void ld16(void* lds, const void* g) {
    __builtin_amdgcn_global_load_lds(
        (const __attribute__((address_space(1))) void*)(uintptr_t)g,
        (__attribute__((address_space(3))) void*)(uint32_t)(uintptr_t)lds,
        16, 0, 0);
}

// ---------------- fused prep: weight transpose x4 + x f32->bf16 ----------------
// z<4: Wt[n][k] = (bf16)W[k][n] for Wq,Wk,Wv,Wp.  z==4: x convert (saves one
// kernel launch; inter-dispatch overhead measured ~15 us/launch).
__global__ __launch_bounds__(1024) void prep_kernel(const float* __restrict__ x,
                                                    const float* __restrict__ W0,
                                                    const float* __restrict__ W1,
                                                    const float* __restrict__ W2,
                                                    const float* __restrict__ W3,
                                                    __bf16* __restrict__ wdst,
                                                    __bf16* __restrict__ xdst) {
    __shared__ __bf16 t[32][33];
    const int z = blockIdx.z;
    const int tx = threadIdx.x, ty = threadIdx.y;
    if (z == 4) {
        // convert path: 1024 blocks-worth folded into 32x32 grid
        int blin = blockIdx.y * 32 + blockIdx.x;
        int i = (blin * 1024 + ty * 32 + tx) * 4;
        float4 v = *(const float4*)(x + i);
        xdst[i]     = (__bf16)v.x;
        xdst[i + 1] = (__bf16)v.y;
        xdst[i + 2] = (__bf16)v.z;
        xdst[i + 3] = (__bf16)v.w;
        return;
    }
    const float* W = (z == 0) ? W0 : (z == 1) ? W1 : (z == 2) ? W2 : W3;
    __bf16* D = wdst + (size_t)z * 1048576;
    t[ty][tx] = (__bf16)W[(size_t)(blockIdx.y * 32 + ty) * 1024 + blockIdx.x * 32 + tx];
    __syncthreads();
    D[(size_t)(blockIdx.x * 32 + ty) * 1024 + blockIdx.y * 32 + tx] = t[tx][ty];
}

// ---------------- shared GEMM mainloop: C[128x128] += A[128xK] * BT[128xK]^T ----
__device__ __forceinline__ void gemm_mainloop(const __bf16* __restrict__ A,
                                              const __bf16* __restrict__ BT,
                                              int K, __bf16* As, __bf16* Bs,
                                              f32x4 acc[4][4]) {
    const int tid  = threadIdx.x;
    const int lane = tid & 63;
    const int wid  = tid >> 6;
    const int quad = lane >> 4;
    const int l16  = lane & 15;
    const int wm   = wid >> 1;
    const int wn   = wid & 1;

    const int srow = wid * 16 + (lane >> 2);
    const int scol = (lane & 3) * 8;
    const int sdst = wid * 512 + lane * 8;

    for (int k0 = 0; k0 < K; k0 += 32) {
        ld16(As + sdst,        A  + (size_t)srow        * K + k0 + scol);
        ld16(As + 2048 + sdst, A  + (size_t)(srow + 64) * K + k0 + scol);
        ld16(Bs + sdst,        BT + (size_t)srow        * K + k0 + scol);
        ld16(Bs + 2048 + sdst, BT + (size_t)(srow + 64) * K + k0 + scol);
        __syncthreads();
        bf16x8 af[4], bf[4];
#pragma unroll
        for (int mt = 0; mt < 4; mt++)
            af[mt] = *(const bf16x8*)(As + (wm * 64 + mt * 16 + l16) * 32 + quad * 8);
#pragma unroll
        for (int nt = 0; nt < 4; nt++)
            bf[nt] = *(const bf16x8*)(Bs + (wn * 64 + nt * 16 + l16) * 32 + quad * 8);
#pragma unroll
        for (int mt = 0; mt < 4; mt++)
#pragma unroll
            for (int nt = 0; nt < 4; nt++)
                acc[mt][nt] = MFMA16(af[mt], bf[nt], acc[mt][nt]);
        __syncthreads();
    }
}

// ---------------- QKV projection: X @ W{q,k,v} + b ------------------------------
// XCD super-tiling (round 3): old grid (8,32,3) gave linear id % 8 == n-column
// -> every XCD streamed all 8 MB of X through its 4 MiB L2 (FETCH 68.7 MB ==
// 8 XCD x 8 MB A + 6 MB B, measured). New 1D grid 768: XCD g owns an 8-row
// m-band x 12-of-24 (n,z) cols; within-XCD rank r walks m fastest, so the
// first 32 resident blocks touch A 2 MB + B 1 MB (< L2). A-panels now fetched
// by 2 XCDs instead of 8.
// z=0 -> Q [B,H,T,HD] PRE-SCALED by (1/8)*log2(e), z=1 -> K, z=2 -> V^T
__global__ __launch_bounds__(256) void qkv_gemm(const __bf16* __restrict__ X,
                                                const __bf16* __restrict__ WTb,
                                                const float* __restrict__ b0,
                                                const float* __restrict__ b1,
                                                const float* __restrict__ b2,
                                                __bf16* __restrict__ qk,
                                                __bf16* __restrict__ vt) {
    __shared__ __attribute__((aligned(16))) __bf16 As[4096];
    __shared__ __attribute__((aligned(16))) __bf16 Bs[4096];
    const int o  = blockIdx.x;
    const int g  = o & 7, r = o >> 3;
    const int mB = ((g >> 1) << 3) + (r & 7);     // m-tile 0..31
    const int nz = (g & 1) * 12 + (r >> 3);       // 0..23
    const int z  = nz >> 3;                       // 0..2
    const int n  = nz & 7;                        // 0..7
    const __bf16* BT   = WTb + (size_t)z * 1048576;
    const float* bias  = (z == 0) ? b0 : (z == 1) ? b1 : b2;
    const int m0 = mB * 128, n0 = n * 128;
    f32x4 acc[4][4];
    const f32x4 zz = {0.f, 0.f, 0.f, 0.f};
#pragma unroll
    for (int i = 0; i < 4; i++)
#pragma unroll
        for (int j = 0; j < 4; j++) acc[i][j] = zz;
    gemm_mainloop(X + (size_t)m0 * 1024, BT + (size_t)n0 * 1024, 1024, As, Bs, acc);

    const int lane = threadIdx.x & 63, wid = threadIdx.x >> 6;
    const int quad = lane >> 4, l16 = lane & 15, wm = wid >> 1, wn = wid & 1;
    if (z == 2) {
        // V^T epilogue: vt[((b*16+h)*64+hd)*2048 + t], 4 consecutive t packed
#pragma unroll
        for (int nt = 0; nt < 4; nt++) {
            int col = n0 + wn * 64 + nt * 16 + l16;
            float bv = bias[col];
            int h = col >> 6, hd = col & 63;
#pragma unroll
            for (int mt = 0; mt < 4; mt++) {
                int m = m0 + wm * 64 + mt * 16 + quad * 4;
                int b = m >> 11, tt = m & 2047;
                bf16x4 pk;
                pk.x = (__bf16)(acc[mt][nt].x + bv);
                pk.y = (__bf16)(acc[mt][nt].y + bv);
                pk.z = (__bf16)(acc[mt][nt].z + bv);
                pk.w = (__bf16)(acc[mt][nt].w + bv);
                *(bf16x4*)(vt + ((size_t)((b * 16 + h) * 64 + hd)) * 2048 + tt) = pk;
            }
        }
    } else {
        // softmax scale (1/sqrt(64))*log2(e) folded into Q here (z==0)
        const float sq = (z == 0) ? 0.18033688011112042f : 1.0f;
        __bf16* dst = qk + (size_t)z * 4194304;
#pragma unroll
        for (int nt = 0; nt < 4; nt++) {
            int col = n0 + wn * 64 + nt * 16 + l16;
            float bv = bias[col];
            int h = col >> 6, hd = col & 63;
#pragma unroll
            for (int mt = 0; mt < 4; mt++) {
#pragma unroll
                for (int r4 = 0; r4 < 4; r4++) {
                    int m = m0 + wm * 64 + mt * 16 + quad * 4 + r4;
                    int b = m >> 11, tt = m & 2047;
                    float v = (acc[mt][nt][r4] + bv) * sq;
                    dst[((size_t)((b * 16 + h) * 2048 + tt)) * 64 + hd] = (__bf16)v;
                }
            }
        }
    }
}

// ---------------- output projection: Y @ Wp + bp -> out [B,T,C] f32 ------------
// XCD super-tiling: XCD g owns 4 m-rows x all 8 n (A 1 MB + B 2 MB resident).
__global__ __launch_bounds__(256) void proj_gemm(const __bf16* __restrict__ Yw,
                                                 const __bf16* __restrict__ WT,
                                                 const float* __restrict__ bias,
                                                 float* __restrict__ out) {
    __shared__ __attribute__((aligned(16))) __bf16 As[4096];
    __shared__ __attribute__((aligned(16))) __bf16 Bs[4096];
    const int o = blockIdx.x;
    const int g = o & 7, r = o >> 3;
    const int m0 = (g * 4 + (r & 3)) * 128;
    const int n0 = (r >> 2) * 128;
    f32x4 acc[4][4];
    const f32x4 zz = {0.f, 0.f, 0.f, 0.f};
#pragma unroll
    for (int i = 0; i < 4; i++)
#pragma unroll
        for (int j = 0; j < 4; j++) acc[i][j] = zz;
    gemm_mainloop(Yw + (size_t)m0 * 1024, WT + (size_t)n0 * 1024, 1024, As, Bs, acc);

    const int lane = threadIdx.x & 63, wid = threadIdx.x >> 6;
    const int quad = lane >> 4, l16 = lane & 15, wm = wid >> 1, wn = wid & 1;
#pragma unroll
    for (int nt = 0; nt < 4; nt++) {
        int col = n0 + wn * 64 + nt * 16 + l16;
        float bv = bias[col];
#pragma unroll
        for (int mt = 0; mt < 4; mt++) {
#pragma unroll
            for (int r4 = 0; r4 < 4; r4++) {
                int m = m0 + wm * 64 + mt * 16 + quad * 4 + r4;
                out[(size_t)m * 1024 + col] = acc[mt][nt][r4] + bv;
            }
        }
    }
}

// ---------------- flash attention v7: q-split waves + LDS-shared K/V ------------
// (unchanged from round 3: ~43 us by subtraction; rocprof counters pending)
__global__ __launch_bounds__(256, 1) void attn_kernel(const __bf16* __restrict__ Qg,
                                                      const __bf16* __restrict__ Kg,
                                                      const __bf16* __restrict__ Vtg,
                                                      __bf16* __restrict__ Y) {
    __shared__ __attribute__((aligned(16))) __bf16 Kb[2][128 * 64];  // [key][d] swz
    __shared__ __attribute__((aligned(16))) __bf16 Vb[2][64 * 128];  // [d][key] swz
    __shared__ __attribute__((aligned(16))) __bf16 Ps[4][32 * 136];  // per-wave P
    __shared__ __attribute__((aligned(16))) float  Lw[4][32];        // per-wave l

    const int tid  = threadIdx.x;
    const int lane = tid & 63;
    const int wid  = tid >> 6;
    const int quad = lane >> 4;
    const int l16  = lane & 15;
    const int bkid = blockIdx.x;
    const int head  = ((bkid & 7) << 2) + ((bkid >> 3) & 3);  // 4 heads per XCD
    const int ipair = bkid >> 5;                              // 0..7
    const size_t hbase = (size_t)head * (2048 * 64);
    const f32x4 zz = {0.f, 0.f, 0.f, 0.f};

    // staging per-lane constants (source pre-swizzle; LDS dest stays linear)
    const int kr  = lane >> 3;            // K row-in-chunk (= row&7)
    const int kc8 = (lane & 7) ^ kr;      // K swizzled 16B slot
    const int vr  = lane >> 4;            // V row-in-chunk
    const int vl  = lane & 15;

#pragma unroll 1
    for (int itm = 0; itm < 2; itm++) {
        const int qi  = itm ? (15 - ipair) : ipair;  // q-tile index == last key tile
        const int ktl = qi;
        const int q0  = qi << 7;
        const int q0w = q0 + wid * 32;

        // Q fragments (B-layout, pre-scaled) for this wave's 32 q rows
        bf16x8 qf[2][2];
#pragma unroll
        for (int nt = 0; nt < 2; nt++)
#pragma unroll
            for (int kk = 0; kk < 2; kk++)
                qf[nt][kk] = *(const bf16x8*)(Qg + hbase +
                                              (size_t)(q0w + nt * 16 + l16) * 64 +
                                              kk * 32 + quad * 8);

        f32x4 acc_o[2][4];
#pragma unroll
        for (int i = 0; i < 2; i++)
#pragma unroll
            for (int jj = 0; jj < 4; jj++) acc_o[i][jj] = zz;
        float l_s[2] = {0.f, 0.f};

        // ---- staging: wave wid stages K chunks 4w..4w+3 (8 rows each) and
        //      V chunks 4w..4w+3 (4 d-rows each); source addr pre-swizzled ----
        auto stage = [&](int bf, int key0) {
#pragma unroll
            for (int i = 0; i < 4; i++) {
                const int c = wid * 4 + i;
                ld16((char*)&Kb[bf][0] + c * 1024 + lane * 16,
                     Kg + hbase + (size_t)(key0 + c * 8 + kr) * 64 + kc8 * 8);
            }
#pragma unroll
            for (int i = 0; i < 4; i++) {
                const int c = wid * 4 + i;
                const int row = c * 4 + vr;
                const int vc  = vl ^ (row & 7);
                ld16((char*)&Vb[bf][0] + c * 1024 + lane * 16,
                     Vtg + hbase + (size_t)row * 2048 + key0 + vc * 8);
            }
        };

        stage(0, 0);
        __syncthreads();   // compiler drains vmcnt before barrier
        int buf = 0;

#pragma unroll 1
        for (int kt = 0; kt <= ktl; kt++) {
            if (kt < ktl) stage(buf ^ 1, (kt + 1) << 7);  // prefetch next tile

            // ---- S^T = K * Q^T from LDS K (swizzled read) ----
            f32x4 accs[8][2];
#pragma unroll
            for (int mt = 0; mt < 8; mt++) { accs[mt][0] = zz; accs[mt][1] = zz; }
#pragma unroll
            for (int kk = 0; kk < 2; kk++) {
#pragma unroll
                for (int mt = 0; mt < 8; mt++) {
                    bf16x8 kf = *(const bf16x8*)(&Kb[buf][(mt * 16 + l16) * 64 +
                                                 (((kk * 4 + quad) ^ (l16 & 7)) << 3)]);
                    accs[mt][0] = MFMA16(kf, qf[0][kk], accs[mt][0]);
                    accs[mt][1] = MFMA16(kf, qf[1][kk], accs[mt][1]);
                }
            }

            // ---- causal mask (diag tile only: item q range == tile ktl) ----
            if (kt == ktl) {
#pragma unroll
                for (int mt = 0; mt < 8; mt++)
#pragma unroll
                    for (int nt = 0; nt < 2; nt++) {
                        int q_g = wid * 32 + nt * 16 + l16;        // rel to q0
#pragma unroll
                        for (int r4 = 0; r4 < 4; r4++) {
                            int key_g = mt * 16 + quad * 4 + r4;   // rel to q0
                            if (key_g > q_g) accs[mt][nt][r4] = -1e30f;
                        }
                    }
            }

            // ---- P = exp2(S^T), no max subtraction; stores to P[q][key] ----
            float s_s[2] = {0.f, 0.f};
#pragma unroll
            for (int mt = 0; mt < 8; mt++)
#pragma unroll
                for (int nt = 0; nt < 2; nt++) {
                    f32x4 pv;
                    pv.x = EXP2(accs[mt][nt].x);
                    pv.y = EXP2(accs[mt][nt].y);
                    pv.z = EXP2(accs[mt][nt].z);
                    pv.w = EXP2(accs[mt][nt].w);
                    s_s[nt] += (pv.x + pv.y) + (pv.z + pv.w);
                    bf16x4 pk;
                    pk.x = (__bf16)pv.x; pk.y = (__bf16)pv.y;
                    pk.z = (__bf16)pv.z; pk.w = (__bf16)pv.w;
                    *(bf16x4*)(&Ps[wid][(nt * 16 + l16) * 136 + mt * 16 + quad * 4]) = pk;
                }
#pragma unroll
            for (int nt = 0; nt < 2; nt++) {
                float t = s_s[nt];
                t += __shfl_xor(t, 16);
                t += __shfl_xor(t, 32);
                l_s[nt] += t;
            }

            // ---- O += P * V (A=P own-wave LDS, B=V shared LDS swizzled) ----
#pragma unroll
            for (int kk = 0; kk < 4; kk++) {
                bf16x8 pf[2], vf[4];
#pragma unroll
                for (int mtP = 0; mtP < 2; mtP++)
                    pf[mtP] = *(const bf16x8*)(&Ps[wid][(mtP * 16 + l16) * 136 +
                                                        kk * 32 + quad * 8]);
#pragma unroll
                for (int nv = 0; nv < 4; nv++)
                    vf[nv] = *(const bf16x8*)(&Vb[buf][(nv * 16 + l16) * 128 +
                                              (((kk * 4 + quad) ^ (l16 & 7)) << 3)]);
#pragma unroll
                for (int mtP = 0; mtP < 2; mtP++)
#pragma unroll
                    for (int nv = 0; nv < 4; nv++)
                        acc_o[mtP][nv] = MFMA16(pf[mtP], vf[nv], acc_o[mtP][nv]);
            }

            __syncthreads();   // all waves done reading buf; staged buf^1 landed
            buf ^= 1;
        }

        // ================= epilogue (wave-owns-rows: no merge) ==================
        if (quad == 0) { Lw[wid][l16] = l_s[0]; Lw[wid][16 + l16] = l_s[1]; }
        // own-wave Ps slice reused as f32 O transpose buffer: [32 q][68 stride]
        float* Om = (float*)&Ps[wid][0];
#pragma unroll
        for (int mtP = 0; mtP < 2; mtP++)
#pragma unroll
            for (int nv = 0; nv < 4; nv++)
#pragma unroll
                for (int r4 = 0; r4 < 4; r4++)
                    Om[(mtP * 16 + quad * 4 + r4) * 68 + nv * 16 + l16] =
                        acc_o[mtP][nv][r4];
        __syncthreads();

        // scale by 1/l, write Y (16B coalesced): lane -> (q = lane/2, 32-d half)
        {
            const int q  = lane >> 1;
            const int d0 = (lane & 1) * 32;
            float li = 1.0f / Lw[wid][q];
            f32x4 s[8];
#pragma unroll
            for (int jj = 0; jj < 8; jj++)
                s[jj] = *(const f32x4*)(&Om[q * 68 + d0 + jj * 4]);
            bf16x8 o0, o1, o2, o3;
            o0[0] = (__bf16)(s[0][0] * li); o0[1] = (__bf16)(s[0][1] * li);
            o0[2] = (__bf16)(s[0][2] * li); o0[3] = (__bf16)(s[0][3] * li);
            o0[4] = (__bf16)(s[1][0] * li); o0[5] = (__bf16)(s[1][1] * li);
            o0[6] = (__bf16)(s[1][2] * li); o0[7] = (__bf16)(s[1][3] * li);
            o1[0] = (__bf16)(s[2][0] * li); o1[1] = (__bf16)(s[2][1] * li);
            o1[2] = (__bf16)(s[2][2] * li); o1[3] = (__bf16)(s[2][3] * li);
            o1[4] = (__bf16)(s[3][0] * li); o1[5] = (__bf16)(s[3][1] * li);
            o1[6] = (__bf16)(s[3][2] * li); o1[7] = (__bf16)(s[3][3] * li);
            o2[0] = (__bf16)(s[4][0] * li); o2[1] = (__bf16)(s[4][1] * li);
            o2[2] = (__bf16)(s[4][2] * li); o2[3] = (__bf16)(s[4][3] * li);
            o2[4] = (__bf16)(s[5][0] * li); o2[5] = (__bf16)(s[5][1] * li);
            o2[6] = (__bf16)(s[5][2] * li); o2[7] = (__bf16)(s[5][3] * li);
            o3[0] = (__bf16)(s[6][0] * li); o3[1] = (__bf16)(s[6][1] * li);
            o3[2] = (__bf16)(s[6][2] * li); o3[3] = (__bf16)(s[6][3] * li);
            o3[4] = (__bf16)(s[7][0] * li); o3[5] = (__bf16)(s[7][1] * li);
            o3[6] = (__bf16)(s[7][2] * li); o3[7] = (__bf16)(s[7][3] * li);
            const int bb = head >> 4, hh = head & 15;
            __bf16* yp = Y + ((size_t)(bb * 2048 + q0w + q)) * 1024 + hh * 64 + d0;
            *(bf16x8*)(yp)      = o0;
            *(bf16x8*)(yp + 8)  = o1;
            *(bf16x8*)(yp + 16) = o2;
            *(bf16x8*)(yp + 24) = o3;
        }
        __syncthreads();   // protect Kb/Vb/Ps reuse by the next item
    }
}

// ws layout (bf16 elems), 40 MB total:
// [0,4Mi)     x as bf16 (dead after qkv) -> reused as Y [B,T,C]
// [4Mi,8Mi)   W^T x4 (Wq,Wk,Wv,Wp)
// [8Mi,12Mi)  Q [B,H,T,HD] (pre-scaled)
// [12Mi,16Mi) K [B,H,T,HD]
// [16Mi,20Mi) V^T [B,H,HD,T]  (written directly by qkv_gemm z=2)
#define XB_OFF  0
#define WT_OFF  4194304
#define Q_OFF   8388608
#define K_OFF   12582912
#define VT_OFF  16777216
#define Y_OFF   0

extern "C" void kernel_launch(void* const* d_in, const int* in_sizes, int n_in,
                              void* d_out, int out_size, void* d_ws, size_t ws_size,
                              hipStream_t stream) {
    const float* x  = (const float*)d_in[0];
    const float* Wq = (const float*)d_in[1];
    const float* bq = (const float*)d_in[2];
    const float* Wk = (const float*)d_in[3];
    const float* bk = (const float*)d_in[4];
    const float* Wv = (const float*)d_in[5];
    const float* bv = (const float*)d_in[6];
    const float* Wp = (const float*)d_in[7];
    const float* bp = (const float*)d_in[8];
    __bf16* ws  = (__bf16*)d_ws;
    float*  out = (float*)d_out;
    if (ws_size < (size_t)41943040) return;  // need 40 MB scratch

    prep_kernel<<<dim3(32, 32, 5), dim3(32, 32), 0, stream>>>(x, Wq, Wk, Wv, Wp,
                                                              ws + WT_OFF, ws + XB_OFF);
    qkv_gemm<<<dim3(768), 256, 0, stream>>>(ws + XB_OFF, ws + WT_OFF, bq, bk, bv,
                                            ws + Q_OFF, ws + VT_OFF);
    attn_kernel<<<dim3(256), 256, 0, stream>>>(ws + Q_OFF, ws + K_OFF, ws + VT_OFF,
                                               ws + Y_OFF);
    proj_gemm<<<dim3(256), 256, 0, stream>>>(ws + Y_OFF, ws + WT_OFF + 3 * 1048576, bp, out);
}

// Round 5
// 177.263 us; speedup vs baseline: 1.5292x; 1.0620x over previous
//
#include <hip/hip_runtime.h>
#include <hip/hip_bf16.h>
#include <stdint.h>

typedef __bf16 bf16x8 __attribute__((ext_vector_type(8)));
typedef __bf16 bf16x4 __attribute__((ext_vector_type(4)));
typedef float  f32x4  __attribute__((ext_vector_type(4)));

#define MFMA16(a, b, c) __builtin_amdgcn_mfma_f32_16x16x32_bf16(a, b, c, 0, 0, 0)

#if __has_builtin(__builtin_amdgcn_exp2f)
#define EXP2(x) __builtin_amdgcn_exp2f(x)
#else
#define EXP2(x) exp2f(x)
#endif

// async 16B global->LDS (dest = wave-uniform base + lane*16)
__device__ __forceinline__ void ld16(void* lds, const void* g) {
    __builtin_amdgcn_global_load_lds(
        (const __attribute__((address_space(1))) void*)(uintptr_t)g,
        (__attribute__((address_space(3))) void*)(uint32_t)(uintptr_t)lds,
        16, 0, 0);
}

// ---------------- fused prep: weight transpose x4 + x f32->bf16 ----------------
__global__ __launch_bounds__(1024) void prep_kernel(const float* __restrict__ x,
                                                    const float* __restrict__ W0,
                                                    const float* __restrict__ W1,
                                                    const float* __restrict__ W2,
                                                    const float* __restrict__ W3,
                                                    __bf16* __restrict__ wdst,
                                                    __bf16* __restrict__ xdst) {
    __shared__ __bf16 t[32][33];
    const int z = blockIdx.z;
    const int tx = threadIdx.x, ty = threadIdx.y;
    if (z == 4) {
        int blin = blockIdx.y * 32 + blockIdx.x;
        int i = (blin * 1024 + ty * 32 + tx) * 4;
        float4 v = *(const float4*)(x + i);
        xdst[i]     = (__bf16)v.x;
        xdst[i + 1] = (__bf16)v.y;
        xdst[i + 2] = (__bf16)v.z;
        xdst[i + 3] = (__bf16)v.w;
        return;
    }
    const float* W = (z == 0) ? W0 : (z == 1) ? W1 : (z == 2) ? W2 : W3;
    __bf16* D = wdst + (size_t)z * 1048576;
    t[ty][tx] = (__bf16)W[(size_t)(blockIdx.y * 32 + ty) * 1024 + blockIdx.x * 32 + tx];
    __syncthreads();
    D[(size_t)(blockIdx.x * 32 + ty) * 1024 + blockIdx.y * 32 + tx] = t[tx][ty];
}

// ---------------- shared GEMM mainloop: C[128x128] += A[128xK] * BT[128xK]^T ----
__device__ __forceinline__ void gemm_mainloop(const __bf16* __restrict__ A,
                                              const __bf16* __restrict__ BT,
                                              int K, __bf16* As, __bf16* Bs,
                                              f32x4 acc[4][4]) {
    const int tid  = threadIdx.x;
    const int lane = tid & 63;
    const int wid  = tid >> 6;
    const int quad = lane >> 4;
    const int l16  = lane & 15;
    const int wm   = wid >> 1;
    const int wn   = wid & 1;

    const int srow = wid * 16 + (lane >> 2);
    const int scol = (lane & 3) * 8;
    const int sdst = wid * 512 + lane * 8;

    for (int k0 = 0; k0 < K; k0 += 32) {
        ld16(As + sdst,        A  + (size_t)srow        * K + k0 + scol);
        ld16(As + 2048 + sdst, A  + (size_t)(srow + 64) * K + k0 + scol);
        ld16(Bs + sdst,        BT + (size_t)srow        * K + k0 + scol);
        ld16(Bs + 2048 + sdst, BT + (size_t)(srow + 64) * K + k0 + scol);
        __syncthreads();
        bf16x8 af[4], bf[4];
#pragma unroll
        for (int mt = 0; mt < 4; mt++)
            af[mt] = *(const bf16x8*)(As + (wm * 64 + mt * 16 + l16) * 32 + quad * 8);
#pragma unroll
        for (int nt = 0; nt < 4; nt++)
            bf[nt] = *(const bf16x8*)(Bs + (wn * 64 + nt * 16 + l16) * 32 + quad * 8);
#pragma unroll
        for (int mt = 0; mt < 4; mt++)
#pragma unroll
            for (int nt = 0; nt < 4; nt++)
                acc[mt][nt] = MFMA16(af[mt], bf[nt], acc[mt][nt]);
        __syncthreads();
    }
}

// ---------------- QKV projection: X @ W{q,k,v} + b ------------------------------
// XCD super-tiling (round 3, verified: FETCH 68.7 -> out of top-5).
// z=0 -> Q [B,H,T,HD] PRE-SCALED by (1/8)*log2(e), z=1 -> K, z=2 -> V^T
__global__ __launch_bounds__(256) void qkv_gemm(const __bf16* __restrict__ X,
                                                const __bf16* __restrict__ WTb,
                                                const float* __restrict__ b0,
                                                const float* __restrict__ b1,
                                                const float* __restrict__ b2,
                                                __bf16* __restrict__ qk,
                                                __bf16* __restrict__ vt) {
    __shared__ __attribute__((aligned(16))) __bf16 As[4096];
    __shared__ __attribute__((aligned(16))) __bf16 Bs[4096];
    const int o  = blockIdx.x;
    const int g  = o & 7, r = o >> 3;
    const int mB = ((g >> 1) << 3) + (r & 7);     // m-tile 0..31
    const int nz = (g & 1) * 12 + (r >> 3);       // 0..23
    const int z  = nz >> 3;                       // 0..2
    const int n  = nz & 7;                        // 0..7
    const __bf16* BT   = WTb + (size_t)z * 1048576;
    const float* bias  = (z == 0) ? b0 : (z == 1) ? b1 : b2;
    const int m0 = mB * 128, n0 = n * 128;
    f32x4 acc[4][4];
    const f32x4 zz = {0.f, 0.f, 0.f, 0.f};
#pragma unroll
    for (int i = 0; i < 4; i++)
#pragma unroll
        for (int j = 0; j < 4; j++) acc[i][j] = zz;
    gemm_mainloop(X + (size_t)m0 * 1024, BT + (size_t)n0 * 1024, 1024, As, Bs, acc);

    const int lane = threadIdx.x & 63, wid = threadIdx.x >> 6;
    const int quad = lane >> 4, l16 = lane & 15, wm = wid >> 1, wn = wid & 1;
    if (z == 2) {
        // V^T epilogue: vt[((b*16+h)*64+hd)*2048 + t], 4 consecutive t packed
#pragma unroll
        for (int nt = 0; nt < 4; nt++) {
            int col = n0 + wn * 64 + nt * 16 + l16;
            float bv = bias[col];
            int h = col >> 6, hd = col & 63;
#pragma unroll
            for (int mt = 0; mt < 4; mt++) {
                int m = m0 + wm * 64 + mt * 16 + quad * 4;
                int b = m >> 11, tt = m & 2047;
                bf16x4 pk;
                pk.x = (__bf16)(acc[mt][nt].x + bv);
                pk.y = (__bf16)(acc[mt][nt].y + bv);
                pk.z = (__bf16)(acc[mt][nt].z + bv);
                pk.w = (__bf16)(acc[mt][nt].w + bv);
                *(bf16x4*)(vt + ((size_t)((b * 16 + h) * 64 + hd)) * 2048 + tt) = pk;
            }
        }
    } else {
        // softmax scale (1/sqrt(64))*log2(e) folded into Q here (z==0)
        const float sq = (z == 0) ? 0.18033688011112042f : 1.0f;
        __bf16* dst = qk + (size_t)z * 4194304;
#pragma unroll
        for (int nt = 0; nt < 4; nt++) {
            int col = n0 + wn * 64 + nt * 16 + l16;
            float bv = bias[col];
            int h = col >> 6, hd = col & 63;
#pragma unroll
            for (int mt = 0; mt < 4; mt++) {
#pragma unroll
                for (int r4 = 0; r4 < 4; r4++) {
                    int m = m0 + wm * 64 + mt * 16 + quad * 4 + r4;
                    int b = m >> 11, tt = m & 2047;
                    float v = (acc[mt][nt][r4] + bv) * sq;
                    dst[((size_t)((b * 16 + h) * 2048 + tt)) * 64 + hd] = (__bf16)v;
                }
            }
        }
    }
}

// ---------------- output projection: Y @ Wp + bp -> out [B,T,C] f32 ------------
__global__ __launch_bounds__(256) void proj_gemm(const __bf16* __restrict__ Yw,
                                                 const __bf16* __restrict__ WT,
                                                 const float* __restrict__ bias,
                                                 float* __restrict__ out) {
    __shared__ __attribute__((aligned(16))) __bf16 As[4096];
    __shared__ __attribute__((aligned(16))) __bf16 Bs[4096];
    const int o = blockIdx.x;
    const int g = o & 7, r = o >> 3;
    const int m0 = (g * 4 + (r & 3)) * 128;
    const int n0 = (r >> 2) * 128;
    f32x4 acc[4][4];
    const f32x4 zz = {0.f, 0.f, 0.f, 0.f};
#pragma unroll
    for (int i = 0; i < 4; i++)
#pragma unroll
        for (int j = 0; j < 4; j++) acc[i][j] = zz;
    gemm_mainloop(Yw + (size_t)m0 * 1024, WT + (size_t)n0 * 1024, 1024, As, Bs, acc);

    const int lane = threadIdx.x & 63, wid = threadIdx.x >> 6;
    const int quad = lane >> 4, l16 = lane & 15, wm = wid >> 1, wn = wid & 1;
#pragma unroll
    for (int nt = 0; nt < 4; nt++) {
        int col = n0 + wn * 64 + nt * 16 + l16;
        float bv = bias[col];
#pragma unroll
        for (int mt = 0; mt < 4; mt++) {
#pragma unroll
            for (int r4 = 0; r4 < 4; r4++) {
                int m = m0 + wm * 64 + mt * 16 + quad * 4 + r4;
                out[(size_t)m * 1024 + col] = acc[mt][nt][r4] + bv;
            }
        }
    }
}

// ---------------- flash attention v8: 8 waves x 16 q-rows -----------------------
// v7 post-mortem: 4 waves/block = 1 wave/SIMD -> zero wave-level overlap;
// 6500 cy/kt-step vs ~1800 issue floor (latency + exp2 chain fully exposed).
// v8: 512-thread blocks, 8 waves each owning 16 q rows of the 128-q item;
// same K/V LDS staging (shared by 8 waves), same swizzles, same no-max
// softmax. 2 waves/SIMD -> one wave's exp2/VALU overlaps the other's MFMA
// (m114), staging latency hidden. LDS ~100 KB unchanged (Ps slices halve).
__global__ __launch_bounds__(512, 1) void attn_kernel(const __bf16* __restrict__ Qg,
                                                      const __bf16* __restrict__ Kg,
                                                      const __bf16* __restrict__ Vtg,
                                                      __bf16* __restrict__ Y) {
    __shared__ __attribute__((aligned(16))) __bf16 Kb[2][128 * 64];  // [key][d] swz
    __shared__ __attribute__((aligned(16))) __bf16 Vb[2][64 * 128];  // [d][key] swz
    __shared__ __attribute__((aligned(16))) __bf16 Ps[8][16 * 136];  // per-wave P
    __shared__ __attribute__((aligned(16))) float  Lw[8][16];        // per-wave l

    const int tid  = threadIdx.x;
    const int lane = tid & 63;
    const int wid  = tid >> 6;          // 0..7
    const int quad = lane >> 4;
    const int l16  = lane & 15;
    const int bkid = blockIdx.x;
    const int head  = ((bkid & 7) << 2) + ((bkid >> 3) & 3);  // 4 heads per XCD
    const int ipair = bkid >> 5;                              // 0..7
    const size_t hbase = (size_t)head * (2048 * 64);
    const f32x4 zz = {0.f, 0.f, 0.f, 0.f};

    // staging per-lane constants (source pre-swizzle; LDS dest stays linear)
    const int kr  = lane >> 3;            // K row-in-chunk (= row&7)
    const int kc8 = (lane & 7) ^ kr;      // K swizzled 16B slot
    const int vr  = lane >> 4;            // V row-in-chunk
    const int vl  = lane & 15;

#pragma unroll 1
    for (int itm = 0; itm < 2; itm++) {
        const int qi  = itm ? (15 - ipair) : ipair;  // q-tile index == last key tile
        const int ktl = qi;
        const int q0  = qi << 7;
        const int q0w = q0 + wid * 16;               // this wave's 16 q rows

        // Q fragments (B-layout, pre-scaled) for this wave's 16 q rows
        bf16x8 qf[2];
#pragma unroll
        for (int kk = 0; kk < 2; kk++)
            qf[kk] = *(const bf16x8*)(Qg + hbase +
                                      (size_t)(q0w + l16) * 64 + kk * 32 + quad * 8);

        f32x4 acc_o[4];
#pragma unroll
        for (int jj = 0; jj < 4; jj++) acc_o[jj] = zz;
        float l_s = 0.f;

        // ---- staging: wave wid stages K chunks 2w..2w+1 (8 rows each) and
        //      V chunks 2w..2w+1 (4 d-rows each); source addr pre-swizzled ----
        auto stage = [&](int bf, int key0) {
#pragma unroll
            for (int i = 0; i < 2; i++) {
                const int c = wid * 2 + i;
                ld16((char*)&Kb[bf][0] + c * 1024 + lane * 16,
                     Kg + hbase + (size_t)(key0 + c * 8 + kr) * 64 + kc8 * 8);
            }
#pragma unroll
            for (int i = 0; i < 2; i++) {
                const int c = wid * 2 + i;
                const int row = c * 4 + vr;
                const int vc  = vl ^ (row & 7);
                ld16((char*)&Vb[bf][0] + c * 1024 + lane * 16,
                     Vtg + hbase + (size_t)row * 2048 + key0 + vc * 8);
            }
        };

        stage(0, 0);
        __syncthreads();   // compiler drains vmcnt before barrier
        int buf = 0;

#pragma unroll 1
        for (int kt = 0; kt <= ktl; kt++) {
            if (kt < ktl) stage(buf ^ 1, (kt + 1) << 7);  // prefetch next tile

            // ---- S^T = K * Q^T from LDS K (swizzled read) ----
            f32x4 accs[8];
#pragma unroll
            for (int mt = 0; mt < 8; mt++) accs[mt] = zz;
#pragma unroll
            for (int kk = 0; kk < 2; kk++) {
#pragma unroll
                for (int mt = 0; mt < 8; mt++) {
                    bf16x8 kf = *(const bf16x8*)(&Kb[buf][(mt * 16 + l16) * 64 +
                                                 (((kk * 4 + quad) ^ (l16 & 7)) << 3)]);
                    accs[mt] = MFMA16(kf, qf[kk], accs[mt]);
                }
            }

            // ---- causal mask (diag tile only: item q range == tile ktl) ----
            if (kt == ktl) {
#pragma unroll
                for (int mt = 0; mt < 8; mt++) {
                    int q_g = wid * 16 + l16;                  // rel to q0
#pragma unroll
                    for (int r4 = 0; r4 < 4; r4++) {
                        int key_g = mt * 16 + quad * 4 + r4;   // rel to q0
                        if (key_g > q_g) accs[mt][r4] = -1e30f;
                    }
                }
            }

            // ---- P = exp2(S^T), no max subtraction; stores to P[q][key] ----
            float s_s = 0.f;
#pragma unroll
            for (int mt = 0; mt < 8; mt++) {
                f32x4 pv;
                pv.x = EXP2(accs[mt].x);
                pv.y = EXP2(accs[mt].y);
                pv.z = EXP2(accs[mt].z);
                pv.w = EXP2(accs[mt].w);
                s_s += (pv.x + pv.y) + (pv.z + pv.w);
                bf16x4 pk;
                pk.x = (__bf16)pv.x; pk.y = (__bf16)pv.y;
                pk.z = (__bf16)pv.z; pk.w = (__bf16)pv.w;
                *(bf16x4*)(&Ps[wid][l16 * 136 + mt * 16 + quad * 4]) = pk;
            }
            {
                float t = s_s;
                t += __shfl_xor(t, 16);
                t += __shfl_xor(t, 32);
                l_s += t;
            }

            // ---- O += P * V (A=P own-wave LDS, B=V shared LDS swizzled) ----
#pragma unroll
            for (int kk = 0; kk < 4; kk++) {
                bf16x8 pf, vf[4];
                pf = *(const bf16x8*)(&Ps[wid][l16 * 136 + kk * 32 + quad * 8]);
#pragma unroll
                for (int nv = 0; nv < 4; nv++)
                    vf[nv] = *(const bf16x8*)(&Vb[buf][(nv * 16 + l16) * 128 +
                                              (((kk * 4 + quad) ^ (l16 & 7)) << 3)]);
#pragma unroll
                for (int nv = 0; nv < 4; nv++)
                    acc_o[nv] = MFMA16(pf, vf[nv], acc_o[nv]);
            }

            __syncthreads();   // all waves done reading buf; staged buf^1 landed
            buf ^= 1;
        }

        // ================= epilogue (wave-owns-rows: no merge) ==================
        if (quad == 0) Lw[wid][l16] = l_s;
        // own-wave Ps slice reused as f32 O transpose buffer: [16 q][68 stride]
        float* Om = (float*)&Ps[wid][0];
#pragma unroll
        for (int nv = 0; nv < 4; nv++)
#pragma unroll
            for (int r4 = 0; r4 < 4; r4++)
                Om[(quad * 4 + r4) * 68 + nv * 16 + l16] = acc_o[nv][r4];
        __syncthreads();

        // scale by 1/l, write Y: lane -> (q = lane>>2, d0 = (lane&3)*16)
        {
            const int q  = lane >> 2;          // 0..15
            const int d0 = (lane & 3) * 16;    // 0,16,32,48
            float li = 1.0f / Lw[wid][q];
            f32x4 s0 = *(const f32x4*)(&Om[q * 68 + d0]);
            f32x4 s1 = *(const f32x4*)(&Om[q * 68 + d0 + 4]);
            f32x4 s2 = *(const f32x4*)(&Om[q * 68 + d0 + 8]);
            f32x4 s3 = *(const f32x4*)(&Om[q * 68 + d0 + 12]);
            bf16x8 o0, o1;
            o0[0] = (__bf16)(s0.x * li); o0[1] = (__bf16)(s0.y * li);
            o0[2] = (__bf16)(s0.z * li); o0[3] = (__bf16)(s0.w * li);
            o0[4] = (__bf16)(s1.x * li); o0[5] = (__bf16)(s1.y * li);
            o0[6] = (__bf16)(s1.z * li); o0[7] = (__bf16)(s1.w * li);
            o1[0] = (__bf16)(s2.x * li); o1[1] = (__bf16)(s2.y * li);
            o1[2] = (__bf16)(s2.z * li); o1[3] = (__bf16)(s2.w * li);
            o1[4] = (__bf16)(s3.x * li); o1[5] = (__bf16)(s3.y * li);
            o1[6] = (__bf16)(s3.z * li); o1[7] = (__bf16)(s3.w * li);
            const int bb = head >> 4, hh = head & 15;
            __bf16* yp = Y + ((size_t)(bb * 2048 + q0w + q)) * 1024 + hh * 64 + d0;
            *(bf16x8*)(yp)     = o0;
            *(bf16x8*)(yp + 8) = o1;
        }
        __syncthreads();   // protect Kb/Vb/Ps reuse by the next item
    }
}

// ws layout (bf16 elems), 40 MB total:
// [0,4Mi)     x as bf16 (dead after qkv) -> reused as Y [B,T,C]
// [4Mi,8Mi)   W^T x4 (Wq,Wk,Wv,Wp)
// [8Mi,12Mi)  Q [B,H,T,HD] (pre-scaled)
// [12Mi,16Mi) K [B,H,T,HD]
// [16Mi,20Mi) V^T [B,H,HD,T]  (written directly by qkv_gemm z=2)
#define XB_OFF  0
#define WT_OFF  4194304
#define Q_OFF   8388608
#define K_OFF   12582912
#define VT_OFF  16777216
#define Y_OFF   0

extern "C" void kernel_launch(void* const* d_in, const int* in_sizes, int n_in,
                              void* d_out, int out_size, void* d_ws, size_t ws_size,
                              hipStream_t stream) {
    const float* x  = (const float*)d_in[0];
    const float* Wq = (const float*)d_in[1];
    const float* bq = (const float*)d_in[2];
    const float* Wk = (const float*)d_in[3];
    const float* bk = (const float*)d_in[4];
    const float* Wv = (const float*)d_in[5];
    const float* bv = (const float*)d_in[6];
    const float* Wp = (const float*)d_in[7];
    const float* bp = (const float*)d_in[8];
    __bf16* ws  = (__bf16*)d_ws;
    float*  out = (float*)d_out;
    if (ws_size < (size_t)41943040) return;  // need 40 MB scratch

    prep_kernel<<<dim3(32, 32, 5), dim3(32, 32), 0, stream>>>(x, Wq, Wk, Wv, Wp,
                                                              ws + WT_OFF, ws + XB_OFF);
    qkv_gemm<<<dim3(768), 256, 0, stream>>>(ws + XB_OFF, ws + WT_OFF, bq, bk, bv,
                                            ws + Q_OFF, ws + VT_OFF);
    attn_kernel<<<dim3(256), 512, 0, stream>>>(ws + Q_OFF, ws + K_OFF, ws + VT_OFF,
                                               ws + Y_OFF);
    proj_gemm<<<dim3(256), 256, 0, stream>>>(ws + Y_OFF, ws + WT_OFF + 3 * 1048576, bp, out);
}